// Round 1
// 229.154 us; speedup vs baseline: 1.1053x; 1.1053x over previous
//
#include <hip/hip_runtime.h>
#include <hip/hip_bf16.h>
#include <math.h>

// Problem constants (reference: B=64, T=2048, D=256)
#define PB 64
#define PT 2048
#define PD 256
#define PM (PB * PT)
#define SBM 64
#define NT (PM / SBM)      // 4096 score tiles
#define TPB (PT / SBM)     // 32 tiles per batch row

typedef __bf16 bf16x8 __attribute__((ext_vector_type(8)));
typedef short  s16x8  __attribute__((ext_vector_type(8)));
typedef float  f32x4  __attribute__((ext_vector_type(4)));

__device__ __forceinline__ short rne_bf16(float x) {
    unsigned u = __builtin_bit_cast(unsigned, x);
    return (short)((u + 0x7fffu + ((u >> 16) & 1u)) >> 16);
}

// split fp32 -> hi (truncated bf16) + lo (RNE bf16 of remainder); hi+lo ~ 2^-17 accurate
__device__ __forceinline__ void split_bf16(float x, short& hi, short& lo) {
    unsigned u = __builtin_bit_cast(unsigned, x);
    hi = (short)(u >> 16);
    float hf = __builtin_bit_cast(float, u & 0xffff0000u);
    lo = rne_bf16(x - hf);
}

// ---------------- Kernel P: pack W into hi/lo bf16 B-fragment order --------
// B[k][e] = W[e][k]. mfma_f32_16x16x32_bf16: lane l holds B[k=(l>>4)*8+j][n=l&15].
// flat = ((nt*8 + kt)*64 + quad*16 + n_loc)*8 + j
__global__ __launch_bounds__(256) void prep_kernel(
    const float* __restrict__ W, short* __restrict__ Whi, short* __restrict__ Wlo)
{
    const int idx = blockIdx.x * 256 + threadIdx.x;   // = e*256 + k
    const int e = idx >> 8;
    const int k = idx & 255;
    short h, l;
    split_bf16(W[idx], h, l);
    const int flat = (((e >> 4) * 8 + (k >> 5)) * 64 + ((k & 31) >> 3) * 16 + (e & 15)) * 8 + (k & 7);
    Whi[flat] = h;
    Wlo[flat] = l;
}

// ---------------- Fused kernel: scores + per-tile softmax stats + moments --
// Per 64-row tile (one b, 64 consecutive t):
//   1. if all rows masked -> write (m=-inf, Z=0), skip everything (exact).
//   2. GEMM: scores = attn . tanh(xs @ W^T + b)  (unchanged MFMA core)
//   3. flash-style: m_loc = max valid score, w_t = exp(s_t - m_loc), Z_loc
//   4. partial moments with UNNORMALIZED w: mu_p = sum w*x, m2_p = sum w*x*x
//      (xs re-read from global -> L2-hot; fp32 precision preserved)
//   5. final reduce kernel rescales by exp(m_loc - M_global) and normalizes.
__global__ __launch_bounds__(256, 4) void score_kernel(
    const float* __restrict__ xs, const short* __restrict__ Whi,
    const short* __restrict__ Wlo, const float* __restrict__ bias,
    const float* __restrict__ attn, const int* __restrict__ mask,
    float* __restrict__ stats, float* __restrict__ part)
{
    // A-fragment-packed LDS: [mt(4)][kt(8)][lane(64)][j(8)] shorts, XOR-swizzled.
    // Reused as float4 reduction scratch in the moment epilogue (dead after GEMM).
    __shared__ __align__(16) short Ah[4 * 8 * 64 * 8];    // 32 KiB
    __shared__ float sred[4][64];
    __shared__ float lw[64];

    const int tid  = threadIdx.x;
    const int tile = blockIdx.x;
    const int bm   = tile * SBM;

    // ---- early exit: fully-masked tile contributes zero weight ----
    const int mv = mask[bm + (tid & 63)];   // same 64 values in every wave
    if (__ballot(mv != 0) == 0ull) {
        if (tid == 0) { stats[tile * 2] = -INFINITY; stats[tile * 2 + 1] = 0.f; }
        return;
    }

    // ---- stage xs tile as RNE bf16 in A-fragment order ----
#pragma unroll
    for (int p = 0; p < 8; ++p) {
        const int r  = p * 8 + (tid >> 5);
        const int kb = tid & 31;                       // 8-elem k-block
        const float4 a0 = *(const float4*)&xs[(bm + r) * PD + kb * 8];
        const float4 a1 = *(const float4*)&xs[(bm + r) * PD + kb * 8 + 4];
        const float f[8] = {a0.x, a0.y, a0.z, a0.w, a1.x, a1.y, a1.z, a1.w};
        s16x8 h;
#pragma unroll
        for (int j = 0; j < 8; ++j) h[j] = rne_bf16(f[j]);
        const int mt = r >> 4, m_loc = r & 15;
        const int kt = kb >> 2, quad = kb & 3;
        const int msw = m_loc ^ (kb & 7);              // bank swizzle
        *(s16x8*)&Ah[(((mt * 8 + kt) * 64) + quad * 16 + msw) * 8] = h;
    }
    __syncthreads();

    const int lane = tid & 63;
    const int w    = tid >> 6;
    const int quad = lane >> 4;
    const int nl   = lane & 15;

    f32x4 acc[4][4] = {};   // [mtile][ntile_local]

#pragma unroll 2
    for (int kt = 0; kt < 8; ++kt) {
        bf16x8 bh[4], bl[4];
#pragma unroll
        for (int n = 0; n < 4; ++n) {
            const int nt = w * 4 + n;
            const int bidx = ((nt * 8 + kt) * 64 + lane) * 8;
            bh[n] = *(const bf16x8*)&Whi[bidx];
            bl[n] = *(const bf16x8*)&Wlo[bidx];
        }
        s16x8 ah[4];
        const int msw = nl ^ ((kt * 4 + quad) & 7);
#pragma unroll
        for (int m = 0; m < 4; ++m)
            ah[m] = *(const s16x8*)&Ah[((m * 8 + kt) * 64 + quad * 16 + msw) * 8];
#pragma unroll
        for (int m = 0; m < 4; ++m) {
            const bf16x8 ahm = __builtin_bit_cast(bf16x8, ah[m]);
#pragma unroll
            for (int n = 0; n < 4; ++n) {
                acc[m][n] = __builtin_amdgcn_mfma_f32_16x16x32_bf16(ahm, bh[n], acc[m][n], 0, 0, 0);
                acc[m][n] = __builtin_amdgcn_mfma_f32_16x16x32_bf16(ahm, bl[n], acc[m][n], 0, 0, 0);
            }
        }
    }

    // ---- epilogue: +bias, tanh, dot attn over e, reduce to per-row scores ----
    float bv[4], av[4];
#pragma unroll
    for (int n = 0; n < 4; ++n) {
        const int col = w * 64 + n * 16 + nl;
        bv[n] = bias[col];
        av[n] = attn[col];
    }
#pragma unroll
    for (int m = 0; m < 4; ++m) {
        float rs[4] = {0.f, 0.f, 0.f, 0.f};
#pragma unroll
        for (int n = 0; n < 4; ++n) {
#pragma unroll
            for (int r = 0; r < 4; ++r) {
                const float u  = acc[m][n][r] + bv[n];
                const float e2 = __expf(2.f * u);                    // inf ok -> th=1
                const float th = 1.f - 2.f * __builtin_amdgcn_rcpf(e2 + 1.f);
                rs[r] = fmaf(th, av[n], rs[r]);
            }
        }
#pragma unroll
        for (int off = 1; off < 16; off <<= 1) {
#pragma unroll
            for (int r = 0; r < 4; ++r) rs[r] += __shfl_xor(rs[r], off);
        }
        if (nl == 0) {
#pragma unroll
            for (int r = 0; r < 4; ++r) sred[w][m * 16 + quad * 4 + r] = rs[r];
        }
    }
    __syncthreads();

    // ---- per-tile masked softmax stats (wave 0 only) ----
    if (tid < 64) {
        float s = sred[0][tid] + sred[1][tid] + sred[2][tid] + sred[3][tid];
        const bool vld = (mv != 0);                    // mv == mask[bm+tid] here
        s = vld ? s : -INFINITY;
        float mx = s;
#pragma unroll
        for (int off = 1; off < 64; off <<= 1) mx = fmaxf(mx, __shfl_xor(mx, off));
        const float wt = vld ? __expf(s - mx) : 0.f;
        float zs = wt;
#pragma unroll
        for (int off = 1; off < 64; off <<= 1) zs += __shfl_xor(zs, off);
        lw[tid] = wt;
        if (tid == 0) { stats[tile * 2] = mx; stats[tile * 2 + 1] = zs; }
    }
    __syncthreads();

    // ---- weighted partial moments over the tile (xs from global, L2-hot) ----
    float4* rmu = (float4*)Ah;            // [4][64], aliases dead Ah
    float4* rm2 = rmu + 4 * 64;
    const int c  = tid & 63;              // float4 column
    const int tq = tid >> 6;              // row group 0..3 (16 rows each)
    float4 mu = {0.f, 0.f, 0.f, 0.f};
    float4 m2 = {0.f, 0.f, 0.f, 0.f};
#pragma unroll
    for (int i = 0; i < 16; ++i) {
        const int r  = tq * 16 + i;
        const float wv = lw[r];
        const float4 x = *(const float4*)&xs[(bm + r) * PD + c * 4];
        mu.x = fmaf(wv, x.x, mu.x); mu.y = fmaf(wv, x.y, mu.y);
        mu.z = fmaf(wv, x.z, mu.z); mu.w = fmaf(wv, x.w, mu.w);
        m2.x = fmaf(wv * x.x, x.x, m2.x); m2.y = fmaf(wv * x.y, x.y, m2.y);
        m2.z = fmaf(wv * x.z, x.z, m2.z); m2.w = fmaf(wv * x.w, x.w, m2.w);
    }
    rmu[tq * 64 + c] = mu;
    rm2[tq * 64 + c] = m2;
    __syncthreads();

    if (tid < 64) {
        float4 smu = rmu[tid], sm2 = rm2[tid];
#pragma unroll
        for (int q = 1; q < 4; ++q) {
            const float4 a = rmu[q * 64 + tid], d = rm2[q * 64 + tid];
            smu.x += a.x; smu.y += a.y; smu.z += a.z; smu.w += a.w;
            sm2.x += d.x; sm2.y += d.y; sm2.z += d.z; sm2.w += d.w;
        }
        const int base = tile * 512;
        *(float4*)&part[base + tid * 4]       = smu;
        *(float4*)&part[base + 256 + tid * 4] = sm2;
    }
}

// ---------------- Final reduce: rescale tiles, normalize, finalize ---------
__global__ __launch_bounds__(256) void finalize_kernel(
    const float* __restrict__ stats, const float* __restrict__ part,
    float* __restrict__ out)
{
    const int b = blockIdx.x;
    const int d = threadIdx.x;

    float M = -INFINITY;
#pragma unroll
    for (int t = 0; t < TPB; ++t) M = fmaxf(M, stats[(b * TPB + t) * 2]);

    float Z = 0.f, m1 = 0.f, m2 = 0.f;
#pragma unroll 4
    for (int t = 0; t < TPB; ++t) {
        const int g = b * TPB + t;
        const float zt = stats[g * 2 + 1];
        if (zt > 0.f) {                                 // uniform branch per block
            const float f = __expf(stats[g * 2] - M);
            Z  = fmaf(zt, f, Z);
            m1 = fmaf(part[g * 512 + d],       f, m1);
            m2 = fmaf(part[g * 512 + 256 + d], f, m2);
        }
    }
    const float inv = 1.f / Z;
    m1 *= inv;
    m2 *= inv;
    const float var = fmaxf(m2 - m1 * m1, 1e-5f);
    out[b * 512 + d]       = m1;
    out[b * 512 + 256 + d] = sqrtf(var);
}

extern "C" void kernel_launch(void* const* d_in, const int* in_sizes, int n_in,
                              void* d_out, int out_size, void* d_ws, size_t ws_size,
                              hipStream_t stream) {
    const float* xs   = (const float*)d_in[0];
    const int*   mask = (const int*)d_in[1];
    // d_in[2] = mask2, unused
    const float* W    = (const float*)d_in[3];
    const float* bias = (const float*)d_in[4];
    const float* attn = (const float*)d_in[5];
    float* out = (float*)d_out;

    float* stats = (float*)d_ws;                     // NT*2 floats (32 KB)
    float* part  = stats + NT * 2;                   // NT*512 floats (8 MB)
    short* Whi   = (short*)(part + NT * 512);        // 65536 shorts
    short* Wlo   = Whi + PD * PD;                    // 65536 shorts

    prep_kernel<<<PD * PD / 256, 256, 0, stream>>>(W, Whi, Wlo);
    score_kernel<<<NT, 256, 0, stream>>>(xs, Whi, Wlo, bias, attn, mask, stats, part);
    finalize_kernel<<<PB, 256, 0, stream>>>(stats, part, out);
}